// Round 1
// baseline (33.500 us; speedup 1.0000x reference)
//
#include <hip/hip_runtime.h>
#include <stdint.h>

typedef _Float16 f16x8 __attribute__((ext_vector_type(8)));
typedef float f32x4 __attribute__((ext_vector_type(4)));

#define MFMA16(a, b, c) __builtin_amdgcn_mfma_f32_16x16x32_f16(a, b, c, 0, 0, 0)

// G[i][k] = (sum_{m<16} W1[i][m] * W3[m][k]) * W2[k][i]
__global__ void cnf_prep(const float* __restrict__ W1, const float* __restrict__ W2,
                         const float* __restrict__ W3, float* __restrict__ G) {
    int idx = blockIdx.x * 256 + threadIdx.x;   // 16384 = 128*128
    int i = idx >> 7, k = idx & 127;
    float m = 0.f;
#pragma unroll
    for (int mm = 0; mm < 16; ++mm) m += W1[i * 17 + mm] * W3[mm * 128 + k];
    G[idx] = m * W2[k * 128 + i];
}

__launch_bounds__(256)
__global__ void cnf_main(const float* __restrict__ y,
                         const float* __restrict__ W1, const float* __restrict__ b1,
                         const float* __restrict__ W2, const float* __restrict__ b2,
                         const float* __restrict__ W3, const float* __restrict__ b3,
                         const float* __restrict__ G, float* __restrict__ out) {
    // [kb = row>>3][col][row&7] f16 subtiled layouts: B-frag read = one ds_read_b128
    __shared__ _Float16 H1[128 * 16];
    __shared__ _Float16 H2[128 * 16];
    __shared__ _Float16 S2[128 * 16];
    __shared__ float YIN[16 * 20];   // [sample][dim], padded stride 20
    __shared__ float TR[4 * 16];     // per-wave trace partials

    const int tid = threadIdx.x;
    const int w   = tid >> 6;    // wave 0..3, owns rows [w*32, w*32+32)
    const int l   = tid & 63;
    const int col = l & 15;      // sample column / A-row within tile
    const int g4  = l >> 4;      // 0..3
    const int sbase = blockIdx.x * 16;

    // ---- stationary weight fragments (live across all 11 evals) ----
    f16x8 W1f[2], W2f[2][4], Gf[2][4];
    float b1r[2][4], b2r[2][4];
#pragma unroll
    for (int m = 0; m < 2; ++m) {
        const int row = w * 32 + m * 16 + col;   // A-frag row = lane&15
        f16x8 a;
#pragma unroll
        for (int j = 0; j < 8; ++j) {
            int k = g4 * 8 + j;
            a[j] = (_Float16)(k < 17 ? W1[row * 17 + k] : 0.f);
        }
        W1f[m] = a;
#pragma unroll
        for (int ks = 0; ks < 4; ++ks) {
            f16x8 aw, ag;
#pragma unroll
            for (int j = 0; j < 8; ++j) {
                int k = ks * 32 + g4 * 8 + j;
                aw[j] = (_Float16)W2[row * 128 + k];
                ag[j] = (_Float16)G[row * 128 + k];
            }
            W2f[m][ks] = aw;
            Gf[m][ks]  = ag;
        }
#pragma unroll
        for (int r = 0; r < 4; ++r) {
            int rr = w * 32 + m * 16 + g4 * 4 + r;  // C-layout row
            b1r[m][r] = b1[rr];
            b2r[m][r] = b2[rr];
        }
    }

    // ---- wave 0 extras: W3, b3, integrator state ----
    f16x8 W3f[4];
    float b3r[4];
    f32x4 yc{}, yh{}, fy{};
    float lc = 0.f, lh = 0.f, fl = 0.f;
    if (w == 0) {
#pragma unroll
        for (int ks = 0; ks < 4; ++ks) {
            f16x8 a;
#pragma unroll
            for (int j = 0; j < 8; ++j)
                a[j] = (_Float16)W3[col * 128 + ks * 32 + g4 * 8 + j];
            W3f[ks] = a;
        }
#pragma unroll
        for (int r = 0; r < 4; ++r) b3r[r] = b3[g4 * 4 + r];
#pragma unroll
        for (int r = 0; r < 4; ++r) {
            float v = y[(sbase + col) * 16 + g4 * 4 + r];
            yc[r] = v;
            yh[r] = v;
            YIN[col * 20 + g4 * 4 + r] = v;   // yin_0 = y
        }
    }

    // 11 vf evals: e=0 initial, e=1..10 the steps (t = e*dt)
    for (int e = 0; e <= 10; ++e) {
        __syncthreads();   // YIN ready
        const float t = 0.1f * (float)e;

        // ---- X B-frag: rows 0..15 = yin, row 16 = t, rest 0 ----
        f16x8 Xf;
#pragma unroll
        for (int j = 0; j < 8; ++j) {
            int k = g4 * 8 + j;
            float v;
            if (k < 16) v = YIN[col * 20 + k];
            else        v = (k == 16) ? t : 0.f;
            Xf[j] = (_Float16)v;
        }

        // ---- layer 1: z1 = W1 @ X + b1 ; h1 -> LDS, s1 -> regs ----
        float s1v[2][4];
#pragma unroll
        for (int m = 0; m < 2; ++m) {
            f32x4 c = {b1r[m][0], b1r[m][1], b1r[m][2], b1r[m][3]};
            c = MFMA16(W1f[m], Xf, c);
            union { _Float16 h[4]; uint32_t u[2]; } pk;
#pragma unroll
            for (int r = 0; r < 4; ++r) {
                float z   = c[r];
                float sig = 1.f / (1.f + __expf(-z));
                float h   = z * sig;
                s1v[m][r] = sig + h * (1.f - sig);   // silu'
                pk.h[r]   = (_Float16)h;
            }
            int rowb = w * 32 + m * 16 + g4 * 4;     // row&7 in {0,4}
            uint32_t* p = (uint32_t*)&H1[(rowb >> 3) * 128 + col * 8 + (rowb & 7)];
            p[0] = pk.u[0];
            p[1] = pk.u[1];
        }
        __syncthreads();   // H1 ready

        // ---- layer 2: z2 = W2 @ H1 + b2 ; h2,s2 -> LDS ----
        f16x8 Bf[4];
#pragma unroll
        for (int ks = 0; ks < 4; ++ks)
            Bf[ks] = *(const f16x8*)&H1[(g4 + ks * 4) * 128 + col * 8];
#pragma unroll
        for (int m = 0; m < 2; ++m) {
            f32x4 c = {b2r[m][0], b2r[m][1], b2r[m][2], b2r[m][3]};
#pragma unroll
            for (int ks = 0; ks < 4; ++ks) c = MFMA16(W2f[m][ks], Bf[ks], c);
            union { _Float16 h[4]; uint32_t u[2]; } pk, ps;
#pragma unroll
            for (int r = 0; r < 4; ++r) {
                float z   = c[r];
                float sig = 1.f / (1.f + __expf(-z));
                float h   = z * sig;
                pk.h[r] = (_Float16)h;
                ps.h[r] = (_Float16)(sig + h * (1.f - sig));
            }
            int rowb = w * 32 + m * 16 + g4 * 4;
            int idx  = (rowb >> 3) * 128 + col * 8 + (rowb & 7);
            uint32_t* p2 = (uint32_t*)&H2[idx];
            p2[0] = pk.u[0]; p2[1] = pk.u[1];
            uint32_t* p3 = (uint32_t*)&S2[idx];
            p3[0] = ps.u[0]; p3[1] = ps.u[1];
        }
        __syncthreads();   // H2, S2 ready

        // ---- trace: p = sum_i s1_i * (G @ s2)_i  (per sample column) ----
#pragma unroll
        for (int ks = 0; ks < 4; ++ks)
            Bf[ks] = *(const f16x8*)&S2[(g4 + ks * 4) * 128 + col * 8];
        float p = 0.f;
#pragma unroll
        for (int m = 0; m < 2; ++m) {
            f32x4 c{};
#pragma unroll
            for (int ks = 0; ks < 4; ++ks) c = MFMA16(Gf[m][ks], Bf[ks], c);
#pragma unroll
            for (int r = 0; r < 4; ++r) p += s1v[m][r] * c[r];
        }
        p += __shfl_xor(p, 16);
        p += __shfl_xor(p, 32);
        if (l < 16) TR[w * 16 + l] = p;

        // ---- wave0: f = W3 @ H2 + b3 ----
        f32x4 fn{};
        if (w == 0) {
            f16x8 Hf[4];
#pragma unroll
            for (int ks = 0; ks < 4; ++ks)
                Hf[ks] = *(const f16x8*)&H2[(g4 + ks * 4) * 128 + col * 8];
            f32x4 c = {b3r[0], b3r[1], b3r[2], b3r[3]};
#pragma unroll
            for (int ks = 0; ks < 4; ++ks) c = MFMA16(W3f[ks], Hf[ks], c);
            fn = c;
        }
        __syncthreads();   // TR ready

        // ---- wave0: integrator update (ReversibleHeun) ----
        if (w == 0) {
            float fln = TR[col] + TR[16 + col] + TR[32 + col] + TR[48 + col];
            if (e == 0) {
                fy = fn; fl = fln;          // initial vf at t0
            } else {
                // y1 = yc + 0.5*dt*(fy + fy1)
#pragma unroll
                for (int r = 0; r < 4; ++r) yc[r] += 0.05f * (fy[r] + fn[r]);
                lc += 0.05f * (fl + fln);
                fy = fn; fl = fln;
            }
            if (e < 10) {
                // yh1 = 2*yc - yh + dt*fy ; next eval input
                f32x4 yhn;
#pragma unroll
                for (int r = 0; r < 4; ++r) {
                    yhn[r] = 2.f * yc[r] - yh[r] + 0.1f * fy[r];
                    YIN[col * 20 + g4 * 4 + r] = yhn[r];
                }
                yh = yhn;
                lh = 2.f * lc - lh + 0.1f * fl;
            }
        }
    }

    // ---- epilogue: out[0..B*16) = y_final, out[B*16..B*17) = l_final ----
    if (w == 0) {
#pragma unroll
        for (int r = 0; r < 4; ++r)
            out[(sbase + col) * 16 + g4 * 4 + r] = yc[r];
        if (l < 16) out[4096 * 16 + sbase + l] = lc;
    }
}

extern "C" void kernel_launch(void* const* d_in, const int* in_sizes, int n_in,
                              void* d_out, int out_size, void* d_ws, size_t ws_size,
                              hipStream_t stream) {
    const float* y  = (const float*)d_in[0];
    const float* W1 = (const float*)d_in[1];
    const float* b1 = (const float*)d_in[2];
    const float* W2 = (const float*)d_in[3];
    const float* b2 = (const float*)d_in[4];
    const float* W3 = (const float*)d_in[5];
    const float* b3 = (const float*)d_in[6];
    float* out = (float*)d_out;
    float* G   = (float*)d_ws;   // 128*128 f32 = 64 KB

    cnf_prep<<<64, 256, 0, stream>>>(W1, W2, W3, G);
    cnf_main<<<256, 256, 0, stream>>>(y, W1, b1, W2, b2, W3, b3, G, out);
}

// Round 2
// 30.355 us; speedup vs baseline: 1.1036x; 1.1036x over previous
//
#include <hip/hip_runtime.h>
#include <stdint.h>

typedef _Float16 f16x8 __attribute__((ext_vector_type(8)));
typedef float f32x4 __attribute__((ext_vector_type(4)));

#define MFMA16(a, b, c) __builtin_amdgcn_mfma_f32_16x16x32_f16(a, b, c, 0, 0, 0)

static __device__ __forceinline__ uint32_t pkh(float a, float b) {
    union { _Float16 h[2]; uint32_t u; } v;
    v.h[0] = (_Float16)a; v.h[1] = (_Float16)b;
    return v.u;
}

// G[i][k] = (sum_{m<16} W1[i][m] * W3[m][k]) * W2[k][i], emitted as f16
__global__ void cnf_prep(const float* __restrict__ W1, const float* __restrict__ W2,
                         const float* __restrict__ W3, _Float16* __restrict__ Gh) {
    int idx = blockIdx.x * 256 + threadIdx.x;   // 16384 = 128*128
    int i = idx >> 7, k = idx & 127;
    float m = 0.f;
#pragma unroll
    for (int mm = 0; mm < 16; ++mm) m += W1[i * 17 + mm] * W3[mm * 128 + k];
    Gh[idx] = (_Float16)(m * W2[k * 128 + i]);
}

__launch_bounds__(256, 1)
__global__ void cnf_main(const float* __restrict__ y,
                         const float* __restrict__ W1, const float* __restrict__ b1,
                         const float* __restrict__ W2, const float* __restrict__ b2,
                         const float* __restrict__ W3, const float* __restrict__ b3,
                         const _Float16* __restrict__ Gh, float* __restrict__ out) {
    // [kb = row>>3][col][row&7] f16 subtiled: B-frag read = one ds_read_b128
    __shared__ _Float16 H1[128 * 16];
    __shared__ _Float16 H2[128 * 16];
    __shared__ _Float16 S2[128 * 16];
    __shared__ float PS[4 * 16];

    const int tid = threadIdx.x;
    const int w   = tid >> 6;    // wave 0..3 owns hidden rows [w*32, w*32+32)
    const int l   = tid & 63;
    const int col = l & 15;      // sample column / A-row-in-tile
    const int g4  = l >> 4;      // 0..3
    const int sbase = blockIdx.x * 16;

    // ---- stationary weight fragments ----
    f16x8 W1f[2], W2f[2][4], Gf[2][4], W3f[4];
    float b1r[2][4], b2r[2][4], b3r[4];
#pragma unroll
    for (int m = 0; m < 2; ++m) {
        const int row = w * 32 + m * 16 + col;
        f16x8 a;
#pragma unroll
        for (int j = 0; j < 8; ++j) {
            int k = g4 * 8 + j;
            a[j] = (_Float16)(k < 17 ? W1[row * 17 + k] : 0.f);
        }
        W1f[m] = a;
#pragma unroll
        for (int ks = 0; ks < 4; ++ks) {
            const float4* pw = (const float4*)&W2[row * 128 + ks * 32 + g4 * 8];
            float4 w0 = pw[0], w1 = pw[1];
            f16x8 aw = {(_Float16)w0.x, (_Float16)w0.y, (_Float16)w0.z, (_Float16)w0.w,
                        (_Float16)w1.x, (_Float16)w1.y, (_Float16)w1.z, (_Float16)w1.w};
            W2f[m][ks] = aw;
            Gf[m][ks]  = *(const f16x8*)&Gh[row * 128 + ks * 32 + g4 * 8];
        }
#pragma unroll
        for (int r = 0; r < 4; ++r) {
            int rr = w * 32 + m * 16 + g4 * 4 + r;
            b1r[m][r] = b1[rr];
            b2r[m][r] = b2[rr];
        }
    }
#pragma unroll
    for (int ks = 0; ks < 4; ++ks) {        // W3 on ALL waves (redundant fn)
        const float4* pw = (const float4*)&W3[col * 128 + ks * 32 + g4 * 8];
        float4 w0 = pw[0], w1 = pw[1];
        f16x8 a = {(_Float16)w0.x, (_Float16)w0.y, (_Float16)w0.z, (_Float16)w0.w,
                   (_Float16)w1.x, (_Float16)w1.y, (_Float16)w1.z, (_Float16)w1.w};
        W3f[ks] = a;
    }
#pragma unroll
    for (int r = 0; r < 4; ++r) b3r[r] = b3[g4 * 4 + r];

    // ---- integrator state, redundant in every wave (C-layout: dim=g4*4+r, sample=col) ----
    f32x4 yc, yh, fy, xsrc;
#pragma unroll
    for (int r = 0; r < 4; ++r) {
        float v = y[(sbase + col) * 16 + g4 * 4 + r];
        yc[r] = v; yh[r] = v; xsrc[r] = v;
    }
    float plsum = 0.f;   // per-wave trapezoid-weighted trace partial

    for (int e = 0; e <= 10; ++e) {
        const float t = 0.1f * (float)e;

        // ---- X B-frag from registers: pack f16 + 4 intra-wave shuffles ----
        uint32_t u0 = pkh(xsrc[0], xsrc[1]);
        uint32_t u1 = pkh(xsrc[2], xsrc[3]);
        int s0 = (g4 * 32 + col) & 63;
        uint32_t xw0 = (uint32_t)__shfl((int)u0, s0);
        uint32_t xw1 = (uint32_t)__shfl((int)u1, s0);
        uint32_t xw2 = (uint32_t)__shfl((int)u0, (s0 + 16) & 63);
        uint32_t xw3 = (uint32_t)__shfl((int)u1, (s0 + 16) & 63);
        if (g4 == 2) { xw0 = pkh(t, 0.f); xw1 = 0u; xw2 = 0u; xw3 = 0u; }
        if (g4 == 3) { xw0 = 0u; xw1 = 0u; xw2 = 0u; xw3 = 0u; }
        union { uint32_t u[4]; f16x8 f; } xu;
        xu.u[0] = xw0; xu.u[1] = xw1; xu.u[2] = xw2; xu.u[3] = xw3;
        f16x8 Xf = xu.f;

        // ---- layer 1: z1 = W1@X + b1 ; h1 -> LDS, silu' -> regs ----
        float s1v[2][4];
#pragma unroll
        for (int m = 0; m < 2; ++m) {
            f32x4 c = {b1r[m][0], b1r[m][1], b1r[m][2], b1r[m][3]};
            c = MFMA16(W1f[m], Xf, c);
            uint32_t pk0, pk1;
            {
                float z0 = c[0], z1 = c[1], z2 = c[2], z3 = c[3];
                float g0 = 1.f / (1.f + __expf(-z0)), g1 = 1.f / (1.f + __expf(-z1));
                float g2 = 1.f / (1.f + __expf(-z2)), g3 = 1.f / (1.f + __expf(-z3));
                float h0 = z0 * g0, h1 = z1 * g1, h2 = z2 * g2, h3 = z3 * g3;
                s1v[m][0] = g0 + h0 * (1.f - g0); s1v[m][1] = g1 + h1 * (1.f - g1);
                s1v[m][2] = g2 + h2 * (1.f - g2); s1v[m][3] = g3 + h3 * (1.f - g3);
                pk0 = pkh(h0, h1); pk1 = pkh(h2, h3);
            }
            int rowb = w * 32 + m * 16 + g4 * 4;
            uint32_t* p = (uint32_t*)&H1[(rowb >> 3) * 128 + col * 8 + (rowb & 7)];
            p[0] = pk0; p[1] = pk1;
        }
        __syncthreads();   // A: H1 ready

        // ---- layer 2: z2 = W2@H1 + b2 ; h2, silu'2 -> LDS ----
        f16x8 Bf[4];
#pragma unroll
        for (int ks = 0; ks < 4; ++ks)
            Bf[ks] = *(const f16x8*)&H1[(g4 + ks * 4) * 128 + col * 8];
#pragma unroll
        for (int m = 0; m < 2; ++m) {
            f32x4 ca = {b2r[m][0], b2r[m][1], b2r[m][2], b2r[m][3]};
            f32x4 cb = {0.f, 0.f, 0.f, 0.f};
            ca = MFMA16(W2f[m][0], Bf[0], ca);
            cb = MFMA16(W2f[m][1], Bf[1], cb);
            ca = MFMA16(W2f[m][2], Bf[2], ca);
            cb = MFMA16(W2f[m][3], Bf[3], cb);
            uint32_t h0u, h1u, s0u, s1u;
            {
                float z0 = ca[0] + cb[0], z1 = ca[1] + cb[1];
                float z2 = ca[2] + cb[2], z3 = ca[3] + cb[3];
                float g0 = 1.f / (1.f + __expf(-z0)), g1 = 1.f / (1.f + __expf(-z1));
                float g2 = 1.f / (1.f + __expf(-z2)), g3 = 1.f / (1.f + __expf(-z3));
                float h0 = z0 * g0, h1 = z1 * g1, h2 = z2 * g2, h3 = z3 * g3;
                h0u = pkh(h0, h1); h1u = pkh(h2, h3);
                s0u = pkh(g0 + h0 * (1.f - g0), g1 + h1 * (1.f - g1));
                s1u = pkh(g2 + h2 * (1.f - g2), g3 + h3 * (1.f - g3));
            }
            int rowb = w * 32 + m * 16 + g4 * 4;
            int idx  = (rowb >> 3) * 128 + col * 8 + (rowb & 7);
            uint32_t* p2 = (uint32_t*)&H2[idx];
            p2[0] = h0u; p2[1] = h1u;
            uint32_t* p3 = (uint32_t*)&S2[idx];
            p3[0] = s0u; p3[1] = s1u;
        }
        __syncthreads();   // B: H2, S2 ready

        // ---- trace partial (per wave, kept in regs) ----
        f16x8 Sf[4], Hf[4];
#pragma unroll
        for (int ks = 0; ks < 4; ++ks) {
            Sf[ks] = *(const f16x8*)&S2[(g4 + ks * 4) * 128 + col * 8];
            Hf[ks] = *(const f16x8*)&H2[(g4 + ks * 4) * 128 + col * 8];
        }
        float p = 0.f;
#pragma unroll
        for (int m = 0; m < 2; ++m) {
            f32x4 c0 = {0.f, 0.f, 0.f, 0.f}, c1 = {0.f, 0.f, 0.f, 0.f};
            c0 = MFMA16(Gf[m][0], Sf[0], c0);
            c1 = MFMA16(Gf[m][1], Sf[1], c1);
            c0 = MFMA16(Gf[m][2], Sf[2], c0);
            c1 = MFMA16(Gf[m][3], Sf[3], c1);
#pragma unroll
            for (int r = 0; r < 4; ++r) p += s1v[m][r] * (c0[r] + c1[r]);
        }
        p += __shfl_xor(p, 16);
        p += __shfl_xor(p, 32);
        plsum += ((e == 0 || e == 10) ? 0.05f : 0.1f) * p;

        // ---- fn = W3@H2 + b3, redundant on all waves ----
        f32x4 fa = {b3r[0], b3r[1], b3r[2], b3r[3]};
        f32x4 fb = {0.f, 0.f, 0.f, 0.f};
        fa = MFMA16(W3f[0], Hf[0], fa);
        fb = MFMA16(W3f[1], Hf[1], fb);
        fa = MFMA16(W3f[2], Hf[2], fa);
        fb = MFMA16(W3f[3], Hf[3], fb);

        // ---- ReversibleHeun update (redundant per wave, all in regs) ----
        if (e == 0) {
#pragma unroll
            for (int r = 0; r < 4; ++r) fy[r] = fa[r] + fb[r];
        } else {
#pragma unroll
            for (int r = 0; r < 4; ++r) {
                float fn = fa[r] + fb[r];
                yc[r] += 0.05f * (fy[r] + fn);
                fy[r] = fn;
            }
        }
        if (e < 10) {
#pragma unroll
            for (int r = 0; r < 4; ++r) {
                float v = 2.f * yc[r] - yh[r] + 0.1f * fy[r];
                xsrc[r] = v;
                yh[r] = v;
            }
        }
    }

    // ---- epilogue: cross-wave trace reduce + outputs ----
    if (l < 16) PS[w * 16 + l] = plsum;
    __syncthreads();
    if (w == 0) {
#pragma unroll
        for (int r = 0; r < 4; ++r)
            out[(sbase + col) * 16 + g4 * 4 + r] = yc[r];
        if (l < 16)
            out[4096 * 16 + sbase + l] = PS[l] + PS[16 + l] + PS[32 + l] + PS[48 + l];
    }
}

extern "C" void kernel_launch(void* const* d_in, const int* in_sizes, int n_in,
                              void* d_out, int out_size, void* d_ws, size_t ws_size,
                              hipStream_t stream) {
    const float* y  = (const float*)d_in[0];
    const float* W1 = (const float*)d_in[1];
    const float* b1 = (const float*)d_in[2];
    const float* W2 = (const float*)d_in[3];
    const float* b2 = (const float*)d_in[4];
    const float* W3 = (const float*)d_in[5];
    const float* b3 = (const float*)d_in[6];
    float* out = (float*)d_out;
    _Float16* Gh = (_Float16*)d_ws;   // 128*128 f16 = 32 KB

    cnf_prep<<<64, 256, 0, stream>>>(W1, W2, W3, Gh);
    cnf_main<<<256, 256, 0, stream>>>(y, W1, b1, W2, b2, W3, b3, Gh, out);
}